// Round 1
// baseline (402.297 us; speedup 1.0000x reference)
//
#include <hip/hip_runtime.h>
#include <stdint.h>

// Problem constants (fixed by reference)
#define T_TOK 32768   // B*S = 8*4096
#define DIN   256
#define DHID  512
#define DOUT  256
#define NEXP  64
#define TM    32      // tokens per expert-FFN block

typedef __attribute__((ext_vector_type(8))) short short8;   // 8 bf16 (4 VGPRs)
typedef __attribute__((ext_vector_type(4))) float f32x4;

// ---- workspace layout (bytes) ----  total ~34.6 MB
#define OFF_W1F   0u                       // 16 MiB bf16 fragment-ordered W1
#define OFF_W2F   16777216u                // 16 MiB bf16 fragment-ordered W2
#define OFF_BASE  33554432u
#define OFF_CNT   (OFF_BASE + 0u)          // 64 int
#define OFF_CUR   (OFF_BASE + 256u)        // 64 int
#define OFF_OFFS  (OFF_BASE + 512u)        // 65 int
#define OFF_TOPKE (OFF_BASE + 1024u)       // 2T int
#define OFF_TOPKG (OFF_TOPKE + 262144u)    // 2T float
#define OFF_PERM  (OFF_TOPKG + 262144u)    // 2T int
#define OFF_PGATE (OFF_PERM + 262144u)     // 2T float

__device__ __forceinline__ unsigned short f2bf(float f) {
    union { float f; unsigned u; } a; a.f = f;
    unsigned u = a.u;
    u += 0x7fffu + ((u >> 16) & 1u);   // RNE
    return (unsigned short)(u >> 16);
}
__device__ __forceinline__ unsigned pack2(float a, float b) {
    return (unsigned)f2bf(a) | ((unsigned)f2bf(b) << 16);
}

// ---------------------------------------------------------------------------
// Convert W1/W2 fp32 -> bf16, pre-swizzled to MFMA B-fragment order:
// per 16(N)x32(K) tile, lane l holds B[k=ktile*32+(l>>4)*8+j][n=ntile*16+(l&15)],
// stored as 64 lanes * 16B contiguous. Tile order: e-major, then n-tile, then k-tile.
// Reads: each wave-instruction covers 4 full 64B lines (no waste). Writes coalesced.
__global__ __launch_bounds__(256) void prep_weights(const float* __restrict__ W1,
                                                    const float* __restrict__ W2,
                                                    uint4* __restrict__ W1f,
                                                    uint4* __restrict__ W2f) {
    int g = blockIdx.x * 256 + threadIdx.x;   // 0 .. 2*2^20-1
    int isW2 = g >> 20;
    int gg = g & ((1 << 20) - 1);
    int l = gg & 63;
    int t = gg >> 6;            // tile id over all experts
    int e = t >> 8;
    int rem = t & 255;
    int quad = l >> 4, lr = l & 15;
    float v[8];
    if (!isW2) {
        int nt = rem >> 3, kt = rem & 7;          // 32 n-tiles, 8 k-tiles
        int kb = kt * 32 + quad * 8;
        int n = nt * 16 + lr;
        const float* s = W1 + (size_t)e * DIN * DHID + n;
#pragma unroll
        for (int j = 0; j < 8; ++j) v[j] = s[(size_t)(kb + j) * DHID];
    } else {
        int nt = rem >> 4, kt = rem & 15;         // 16 n-tiles, 16 k-tiles
        int kb = kt * 32 + quad * 8;
        int n = nt * 16 + lr;
        const float* s = W2 + (size_t)e * DHID * DOUT + n;
#pragma unroll
        for (int j = 0; j < 8; ++j) v[j] = s[(size_t)(kb + j) * DOUT];
    }
    uint4 o;
    o.x = pack2(v[0], v[1]); o.y = pack2(v[2], v[3]);
    o.z = pack2(v[4], v[5]); o.w = pack2(v[6], v[7]);
    (isW2 ? W2f : W1f)[gg] = o;
}

// ---------------------------------------------------------------------------
// Router: fp32 logits (must be fp32 — bf16 would swap near-tie top-2 picks),
// 64 tokens x 64 experts per block via register-tiled outer product,
// then per-wave butterfly top-2 (tie -> lower index) + 2-way softmax.
__global__ __launch_bounds__(256) void router_kernel(const float* __restrict__ x,
                                                     const float* __restrict__ Wr,
                                                     const float* __restrict__ br,
                                                     int* __restrict__ topk_e,
                                                     float* __restrict__ topk_g) {
    __shared__ float xl[64][68];   // x chunk [tok][d], later reused for logits [tok][e]
    __shared__ float wt[64][68];   // Wr transposed chunk [e][d]
    int tid = threadIdx.x;
    int a = tid >> 4;        // expert group base
    int bcol = tid & 15;     // token group base
    int tok0 = blockIdx.x * 64;
    float c[4][4];
#pragma unroll
    for (int i = 0; i < 4; ++i)
#pragma unroll
        for (int j = 0; j < 4; ++j) c[i][j] = 0.0f;

    for (int chunk = 0; chunk < 4; ++chunk) {
        int d0 = chunk * 64;
        {   // stage x[tok0..tok0+63][d0..d0+63]
            int tok = tid >> 2, off = (tid & 3) * 16;
            const float4* s = (const float4*)(x + (size_t)(tok0 + tok) * DIN + d0 + off);
            float4* d = (float4*)&xl[tok][off];
#pragma unroll
            for (int i = 0; i < 4; ++i) d[i] = s[i];
        }
        {   // stage Wr chunk transposed: wt[e][dd] = Wr[d0+dd][e]
            int dd = tid >> 2, ecol = (tid & 3) * 16;
            const float* s = Wr + (size_t)(d0 + dd) * NEXP + ecol;
#pragma unroll
            for (int j = 0; j < 16; ++j) wt[ecol + j][dd] = s[j];
        }
        __syncthreads();
#pragma unroll 4
        for (int d = 0; d < 64; d += 4) {
            float4 xv[4], wv[4];
#pragma unroll
            for (int i = 0; i < 4; ++i) xv[i] = *(const float4*)&xl[bcol + i * 16][d];
#pragma unroll
            for (int j = 0; j < 4; ++j) wv[j] = *(const float4*)&wt[a + j * 16][d];
#pragma unroll
            for (int i = 0; i < 4; ++i)
#pragma unroll
                for (int j = 0; j < 4; ++j) {
                    c[i][j] = fmaf(xv[i].x, wv[j].x, c[i][j]);
                    c[i][j] = fmaf(xv[i].y, wv[j].y, c[i][j]);
                    c[i][j] = fmaf(xv[i].z, wv[j].z, c[i][j]);
                    c[i][j] = fmaf(xv[i].w, wv[j].w, c[i][j]);
                }
        }
        __syncthreads();
    }
    // write logits (+bias) into xl[tok][e]
#pragma unroll
    for (int i = 0; i < 4; ++i)
#pragma unroll
        for (int j = 0; j < 4; ++j)
            xl[bcol + i * 16][a + j * 16] = c[i][j] + br[a + j * 16];
    __syncthreads();

    int w = tid >> 6, lane = tid & 63;
    for (int ti = 0; ti < 16; ++ti) {
        int tl = w * 16 + ti;
        float acc = xl[tl][lane];     // lane == expert
        float v = acc; int idx = lane;
#pragma unroll
        for (int m = 32; m; m >>= 1) {
            float ov = __shfl_xor(v, m); int oi = __shfl_xor(idx, m);
            if (ov > v || (ov == v && oi < idx)) { v = ov; idx = oi; }
        }
        int e0 = idx; float l0 = v;
        float v2 = (lane == e0) ? -3.4e38f : acc; int idx2 = lane;
#pragma unroll
        for (int m = 32; m; m >>= 1) {
            float ov = __shfl_xor(v2, m); int oi = __shfl_xor(idx2, m);
            if (ov > v2 || (ov == v2 && oi < idx2)) { v2 = ov; idx2 = oi; }
        }
        if (lane == 0) {
            int t = tok0 + tl;
            float ex = expf(v2 - l0);         // <= 1
            float g1 = ex / (1.0f + ex);
            topk_e[2 * t] = e0; topk_e[2 * t + 1] = idx2;
            topk_g[2 * t] = 1.0f - g1; topk_g[2 * t + 1] = g1;
        }
    }
}

// ---------------------------------------------------------------------------
__global__ __launch_bounds__(256) void count_kernel(const int* __restrict__ topk_e,
                                                    int* __restrict__ cnt) {
    __shared__ int lcnt[NEXP];
    int tid = threadIdx.x;
    if (tid < NEXP) lcnt[tid] = 0;
    __syncthreads();
    int t = blockIdx.x * 256 + tid;
    atomicAdd(&lcnt[topk_e[2 * t]], 1);
    atomicAdd(&lcnt[topk_e[2 * t + 1]], 1);
    __syncthreads();
    if (tid < NEXP) atomicAdd(&cnt[tid], lcnt[tid]);
}

__global__ void scan_kernel(const int* __restrict__ cnt, int* __restrict__ offs,
                            int* __restrict__ cursor) {
    if (threadIdx.x == 0) {
        int s = 0;
        for (int e = 0; e < NEXP; ++e) { offs[e] = s; s += cnt[e]; }
        offs[NEXP] = s;
    }
    if (threadIdx.x < NEXP) cursor[threadIdx.x] = 0;
}

__global__ __launch_bounds__(256) void scatter_kernel(const int* __restrict__ topk_e,
                                                      const float* __restrict__ topk_g,
                                                      const int* __restrict__ offs,
                                                      int* __restrict__ cursor,
                                                      int* __restrict__ perm,
                                                      float* __restrict__ pgate) {
    __shared__ int lcnt[NEXP], lbase[NEXP];
    int tid = threadIdx.x;
    if (tid < NEXP) lcnt[tid] = 0;
    __syncthreads();
    int t = blockIdx.x * 256 + tid;
    int e0 = topk_e[2 * t], e1 = topk_e[2 * t + 1];
    int i0 = atomicAdd(&lcnt[e0], 1);
    int i1 = atomicAdd(&lcnt[e1], 1);
    __syncthreads();
    if (tid < NEXP) lbase[tid] = atomicAdd(&cursor[tid], lcnt[tid]);
    __syncthreads();
    int p0 = offs[e0] + lbase[e0] + i0;
    int p1 = offs[e1] + lbase[e1] + i1;
    perm[p0] = t; pgate[p0] = topk_g[2 * t];
    perm[p1] = t; pgate[p1] = topk_g[2 * t + 1];
}

// ---------------------------------------------------------------------------
// Expert FFN: one block = (expert e, tile of TM=32 tokens), 4 waves.
// Wave w: M-tile (w&1) (16 tokens), N-half (w>>1).
// A-frags from LDS (x / h staged bf16, +8 ushort pad -> 2-way bank alias = free),
// B-frags straight from global (fragment-ordered, 1 dwordx4/lane/MFMA).
// MFMA 16x16x32 bf16; layouts: A[m=lane&15][k=(lane>>4)*8+j];
// C/D: col=lane&15, row=(lane>>4)*4+reg.
__global__ __launch_bounds__(256) void expert_ffn(const float* __restrict__ x,
                                                  const uint4* __restrict__ W1f,
                                                  const uint4* __restrict__ W2f,
                                                  const float* __restrict__ b1,
                                                  const float* __restrict__ b2,
                                                  const int* __restrict__ cnt,
                                                  const int* __restrict__ offs,
                                                  const int* __restrict__ perm,
                                                  const float* __restrict__ pgate,
                                                  float* __restrict__ out) {
    int e = blockIdx.y;
    int ne = cnt[e];
    int tile0 = blockIdx.x * TM;
    if (tile0 >= ne) return;

    __shared__ unsigned short xs[TM][DIN + 8];    // 16.5 KB
    __shared__ unsigned short hs[TM][DHID + 8];   // 32.5 KB
    __shared__ int toks[TM];
    __shared__ float gs[TM];

    int tid = threadIdx.x;
    if (tid < TM) {
        int idx = tile0 + tid;
        if (idx < ne) {
            int p = offs[e] + idx;
            toks[tid] = perm[p]; gs[tid] = pgate[p];
        } else {
            toks[tid] = 0; gs[tid] = 0.0f;   // padded slot: gate 0 -> no-op add
        }
    }
    __syncthreads();
    {   // gather x rows -> LDS bf16
        int row = tid >> 3, c0 = (tid & 7) * 32;
        const float4* src = (const float4*)(x + (size_t)toks[row] * DIN + c0);
        unsigned* dst = (unsigned*)&xs[row][c0];
#pragma unroll
        for (int i = 0; i < 8; ++i) {
            float4 v = src[i];
            dst[2 * i]     = pack2(v.x, v.y);
            dst[2 * i + 1] = pack2(v.z, v.w);
        }
    }
    __syncthreads();

    int w = tid >> 6, lane = tid & 63;
    int quad = lane >> 4, lr = lane & 15;
    int m0 = (w & 1) * 16;

    // ---- layer 1: H = relu(X @ W1[e] + b1[e]) ----
    short8 a1[8];
#pragma unroll
    for (int kk = 0; kk < 8; ++kk)
        a1[kk] = *(const short8*)&xs[m0 + lr][kk * 32 + quad * 8];
    int nbase1 = (w >> 1) * 256;
    for (int nt = 0; nt < 16; ++nt) {
        int n = nbase1 + nt * 16;
        f32x4 acc = {0.0f, 0.0f, 0.0f, 0.0f};
        const uint4* bp = W1f + (size_t)e * 16384 + (size_t)((n >> 4) * 8) * 64 + lane;
#pragma unroll
        for (int kk = 0; kk < 8; ++kk) {
            uint4 braw = bp[kk * 64];
            acc = __builtin_amdgcn_mfma_f32_16x16x32_bf16(
                a1[kk], __builtin_bit_cast(short8, braw), acc, 0, 0, 0);
        }
        float bias = b1[e * DHID + n + lr];
#pragma unroll
        for (int r = 0; r < 4; ++r) {
            float h = fmaxf(acc[r] + bias, 0.0f);
            hs[m0 + quad * 4 + r][n + lr] = f2bf(h);
        }
    }
    __syncthreads();

    // ---- layer 2: Y = H @ W2[e] + b2[e], out += g*Y ----
    short8 a2[16];
#pragma unroll
    for (int kk = 0; kk < 16; ++kk)
        a2[kk] = *(const short8*)&hs[m0 + lr][kk * 32 + quad * 8];
    int tokr[4]; float gr[4];
#pragma unroll
    for (int r = 0; r < 4; ++r) {
        int m = m0 + quad * 4 + r;
        tokr[r] = toks[m]; gr[r] = gs[m];
    }
    int nbase2 = (w >> 1) * 128;
    for (int nt = 0; nt < 8; ++nt) {
        int n = nbase2 + nt * 16;
        f32x4 acc = {0.0f, 0.0f, 0.0f, 0.0f};
        const uint4* bp = W2f + (size_t)e * 16384 + (size_t)((n >> 4) * 16) * 64 + lane;
#pragma unroll
        for (int kk = 0; kk < 16; ++kk) {
            uint4 braw = bp[kk * 64];
            acc = __builtin_amdgcn_mfma_f32_16x16x32_bf16(
                a2[kk], __builtin_bit_cast(short8, braw), acc, 0, 0, 0);
        }
        float bias = b2[e * DOUT + n + lr];
#pragma unroll
        for (int r = 0; r < 4; ++r) {
            float y = acc[r] + bias;
            atomicAdd(&out[(size_t)tokr[r] * DOUT + n + lr], gr[r] * y);
        }
    }
}

// ---------------------------------------------------------------------------
extern "C" void kernel_launch(void* const* d_in, const int* in_sizes, int n_in,
                              void* d_out, int out_size, void* d_ws, size_t ws_size,
                              hipStream_t stream) {
    (void)in_sizes; (void)n_in; (void)ws_size;   // needs ws_size >= ~34.6 MB
    const float* x  = (const float*)d_in[0];
    const float* Wr = (const float*)d_in[1];
    const float* br = (const float*)d_in[2];
    const float* W1 = (const float*)d_in[3];
    const float* b1 = (const float*)d_in[4];
    const float* W2 = (const float*)d_in[5];
    const float* b2 = (const float*)d_in[6];
    float* out = (float*)d_out;
    char* ws = (char*)d_ws;

    uint4* W1f    = (uint4*)(ws + OFF_W1F);
    uint4* W2f    = (uint4*)(ws + OFF_W2F);
    int*   cnt    = (int*)(ws + OFF_CNT);
    int*   cursor = (int*)(ws + OFF_CUR);
    int*   offs   = (int*)(ws + OFF_OFFS);
    int*   topk_e = (int*)(ws + OFF_TOPKE);
    float* topk_g = (float*)(ws + OFF_TOPKG);
    int*   perm   = (int*)(ws + OFF_PERM);
    float* pgate  = (float*)(ws + OFF_PGATE);

    hipMemsetAsync(out, 0, (size_t)out_size * sizeof(float), stream);
    hipMemsetAsync(ws + OFF_CNT, 0, 512, stream);   // cnt + cursor

    prep_weights<<<8192, 256, 0, stream>>>(W1, W2, W1f, W2f);
    router_kernel<<<T_TOK / 64, 256, 0, stream>>>(x, Wr, br, topk_e, topk_g);
    count_kernel<<<T_TOK / 256, 256, 0, stream>>>(topk_e, cnt);
    scan_kernel<<<1, 64, 0, stream>>>(cnt, offs, cursor);
    scatter_kernel<<<T_TOK / 256, 256, 0, stream>>>(topk_e, topk_g, offs, cursor, perm, pgate);
    expert_ffn<<<dim3(1024, NEXP), 256, 0, stream>>>(x, W1f, W2f, b1, b2, cnt, offs,
                                                     perm, pgate, out);
}

// Round 2
// 365.277 us; speedup vs baseline: 1.1013x; 1.1013x over previous
//
#include <hip/hip_runtime.h>
#include <stdint.h>

// Problem constants (fixed by reference)
#define T_TOK 32768   // B*S = 8*4096
#define DIN   256
#define DHID  512
#define DOUT  256
#define NEXP  64
#define TM    32      // tokens per expert-FFN block
#define MAXTILES (2 * T_TOK / TM + NEXP)   // 2112 upper bound on sum ceil(cnt/TM)

typedef __attribute__((ext_vector_type(8))) short short8;   // 8 bf16 (4 VGPRs)
typedef __attribute__((ext_vector_type(4))) float f32x4;

// ---- workspace layout (bytes) ----  total ~34.6 MB
#define OFF_W1F   0u                       // 16 MiB bf16 fragment-ordered W1
#define OFF_W2F   16777216u                // 16 MiB bf16 fragment-ordered W2
#define OFF_BASE  33554432u
#define OFF_CNT   (OFF_BASE + 0u)          // 64 int
#define OFF_CUR   (OFF_BASE + 256u)        // 64 int
#define OFF_OFFS  (OFF_BASE + 512u)        // 65 int
#define OFF_TILE  (OFF_BASE + 1024u)       // 65 int (tile-count prefix)
#define OFF_TOPKE (OFF_BASE + 2048u)       // 2T int
#define OFF_TOPKG (OFF_TOPKE + 262144u)    // 2T float
#define OFF_PERM  (OFF_TOPKG + 262144u)    // 2T int
#define OFF_PGATE (OFF_PERM + 262144u)     // 2T float

__device__ __forceinline__ unsigned short f2bf(float f) {
    union { float f; unsigned u; } a; a.f = f;
    unsigned u = a.u;
    u += 0x7fffu + ((u >> 16) & 1u);   // RNE
    return (unsigned short)(u >> 16);
}
__device__ __forceinline__ unsigned pack2(float a, float b) {
    return (unsigned)f2bf(a) | ((unsigned)f2bf(b) << 16);
}

// ---------------------------------------------------------------------------
// Convert W1/W2 fp32 -> bf16, pre-swizzled to MFMA B-fragment order:
// per 16(N)x32(K) tile, lane l holds B[k=kt*32+(l>>4)*8+j][n=nt*16+(l&15)],
// stored as 64 lanes * 16B contiguous. Tile order: e-major, then n-tile, then k-tile.
__global__ __launch_bounds__(256) void prep_weights(const float* __restrict__ W1,
                                                    const float* __restrict__ W2,
                                                    uint4* __restrict__ W1f,
                                                    uint4* __restrict__ W2f) {
    int g = blockIdx.x * 256 + threadIdx.x;   // 0 .. 2*2^20-1
    int isW2 = g >> 20;
    int gg = g & ((1 << 20) - 1);
    int l = gg & 63;
    int t = gg >> 6;            // tile id over all experts
    int e = t >> 8;
    int rem = t & 255;
    int quad = l >> 4, lr = l & 15;
    float v[8];
    if (!isW2) {
        int nt = rem >> 3, kt = rem & 7;          // 32 n-tiles, 8 k-tiles
        int kb = kt * 32 + quad * 8;
        int n = nt * 16 + lr;
        const float* s = W1 + (size_t)e * DIN * DHID + n;
#pragma unroll
        for (int j = 0; j < 8; ++j) v[j] = s[(size_t)(kb + j) * DHID];
    } else {
        int nt = rem >> 4, kt = rem & 15;         // 16 n-tiles, 16 k-tiles
        int kb = kt * 32 + quad * 8;
        int n = nt * 16 + lr;
        const float* s = W2 + (size_t)e * DHID * DOUT + n;
#pragma unroll
        for (int j = 0; j < 8; ++j) v[j] = s[(size_t)(kb + j) * DOUT];
    }
    uint4 o;
    o.x = pack2(v[0], v[1]); o.y = pack2(v[2], v[3]);
    o.z = pack2(v[4], v[5]); o.w = pack2(v[6], v[7]);
    (isW2 ? W2f : W1f)[gg] = o;
}

// ---------------------------------------------------------------------------
// Router: fp32 logits (bf16 would swap near-tie top-2 picks), 64 tok x 64 exp
// per block, register-tiled outer product, butterfly top-2 + 2-way softmax.
// Count fused: per-block LDS histogram -> 64 global atomics.
__global__ __launch_bounds__(256) void router_kernel(const float* __restrict__ x,
                                                     const float* __restrict__ Wr,
                                                     const float* __restrict__ br,
                                                     int* __restrict__ topk_e,
                                                     float* __restrict__ topk_g,
                                                     int* __restrict__ cnt) {
    __shared__ float xl[64][68];   // x chunk [tok][d], later logits [tok][e]
    __shared__ float wt[64][68];   // Wr transposed chunk [e][d]
    __shared__ int lcnt[NEXP];
    int tid = threadIdx.x;
    if (tid < NEXP) lcnt[tid] = 0;
    int a = tid >> 4;        // expert group base
    int bcol = tid & 15;     // token group base
    int tok0 = blockIdx.x * 64;
    float c[4][4];
#pragma unroll
    for (int i = 0; i < 4; ++i)
#pragma unroll
        for (int j = 0; j < 4; ++j) c[i][j] = 0.0f;

    for (int chunk = 0; chunk < 4; ++chunk) {
        int d0 = chunk * 64;
        {   // stage x[tok0..tok0+63][d0..d0+63]
            int tok = tid >> 2, off = (tid & 3) * 16;
            const float4* s = (const float4*)(x + (size_t)(tok0 + tok) * DIN + d0 + off);
            float4* d = (float4*)&xl[tok][off];
#pragma unroll
            for (int i = 0; i < 4; ++i) d[i] = s[i];
        }
        {   // stage Wr chunk transposed: wt[e][dd] = Wr[d0+dd][e]
            int dd = tid >> 2, ecol = (tid & 3) * 16;
            const float* s = Wr + (size_t)(d0 + dd) * NEXP + ecol;
#pragma unroll
            for (int j = 0; j < 16; ++j) wt[ecol + j][dd] = s[j];
        }
        __syncthreads();
#pragma unroll 4
        for (int d = 0; d < 64; d += 4) {
            float4 xv[4], wv[4];
#pragma unroll
            for (int i = 0; i < 4; ++i) xv[i] = *(const float4*)&xl[bcol + i * 16][d];
#pragma unroll
            for (int j = 0; j < 4; ++j) wv[j] = *(const float4*)&wt[a + j * 16][d];
#pragma unroll
            for (int i = 0; i < 4; ++i)
#pragma unroll
                for (int j = 0; j < 4; ++j) {
                    c[i][j] = fmaf(xv[i].x, wv[j].x, c[i][j]);
                    c[i][j] = fmaf(xv[i].y, wv[j].y, c[i][j]);
                    c[i][j] = fmaf(xv[i].z, wv[j].z, c[i][j]);
                    c[i][j] = fmaf(xv[i].w, wv[j].w, c[i][j]);
                }
        }
        __syncthreads();
    }
#pragma unroll
    for (int i = 0; i < 4; ++i)
#pragma unroll
        for (int j = 0; j < 4; ++j)
            xl[bcol + i * 16][a + j * 16] = c[i][j] + br[a + j * 16];
    __syncthreads();

    int w = tid >> 6, lane = tid & 63;
    for (int ti = 0; ti < 16; ++ti) {
        int tl = w * 16 + ti;
        float acc = xl[tl][lane];     // lane == expert
        float v = acc; int idx = lane;
#pragma unroll
        for (int m = 32; m; m >>= 1) {
            float ov = __shfl_xor(v, m); int oi = __shfl_xor(idx, m);
            if (ov > v || (ov == v && oi < idx)) { v = ov; idx = oi; }
        }
        int e0 = idx; float l0 = v;
        float v2 = (lane == e0) ? -3.4e38f : acc; int idx2 = lane;
#pragma unroll
        for (int m = 32; m; m >>= 1) {
            float ov = __shfl_xor(v2, m); int oi = __shfl_xor(idx2, m);
            if (ov > v2 || (ov == v2 && oi < idx2)) { v2 = ov; idx2 = oi; }
        }
        if (lane == 0) {
            int t = tok0 + tl;
            float ex = expf(v2 - l0);         // <= 1
            float g1 = ex / (1.0f + ex);
            topk_e[2 * t] = e0; topk_e[2 * t + 1] = idx2;
            topk_g[2 * t] = 1.0f - g1; topk_g[2 * t + 1] = g1;
            atomicAdd(&lcnt[e0], 1);
            atomicAdd(&lcnt[idx2], 1);
        }
    }
    __syncthreads();
    if (tid < NEXP) atomicAdd(&cnt[tid], lcnt[tid]);
}

// ---------------------------------------------------------------------------
// One wave: exclusive scans of cnt (slot offsets) and ceil(cnt/TM) (tile offsets).
__global__ void scan_kernel(const int* __restrict__ cnt, int* __restrict__ offs,
                            int* __restrict__ tileOffs, int* __restrict__ cursor) {
    int lane = threadIdx.x;   // 64 threads
    int c = cnt[lane];
    int t = (c + TM - 1) / TM;
    int ic = c, it = t;
#pragma unroll
    for (int d = 1; d < 64; d <<= 1) {
        int vc = __shfl_up(ic, d), vt = __shfl_up(it, d);
        if (lane >= d) { ic += vc; it += vt; }
    }
    offs[lane] = ic - c;
    tileOffs[lane] = it - t;
    if (lane == 63) { offs[64] = ic; tileOffs[64] = it; }
    cursor[lane] = 0;
}

__global__ __launch_bounds__(256) void scatter_kernel(const int* __restrict__ topk_e,
                                                      const float* __restrict__ topk_g,
                                                      const int* __restrict__ offs,
                                                      int* __restrict__ cursor,
                                                      int* __restrict__ perm,
                                                      float* __restrict__ pgate) {
    __shared__ int lcnt[NEXP], lbase[NEXP];
    int tid = threadIdx.x;
    if (tid < NEXP) lcnt[tid] = 0;
    __syncthreads();
    int t = blockIdx.x * 256 + tid;
    int e0 = topk_e[2 * t], e1 = topk_e[2 * t + 1];
    int i0 = atomicAdd(&lcnt[e0], 1);
    int i1 = atomicAdd(&lcnt[e1], 1);
    __syncthreads();
    if (tid < NEXP) lbase[tid] = atomicAdd(&cursor[tid], lcnt[tid]);
    __syncthreads();
    int p0 = offs[e0] + lbase[e0] + i0;
    int p1 = offs[e1] + lbase[e1] + i1;
    perm[p0] = t; pgate[p0] = topk_g[2 * t];
    perm[p1] = t; pgate[p1] = topk_g[2 * t + 1];
}

// ---------------------------------------------------------------------------
// Expert FFN v2: grid = exact tile list (binary search tileOffs). 4 waves/block.
// Wave w owns N-quarter (disjoint!) and computes BOTH 16-row m-tiles per B
// fragment -> W1+W2 read exactly once per block (512 KB), 2 MFMAs per B load.
// LDS union: x-tile (cols 0..255) is consumed into regs before layer1, then
// the same buffer holds H (cols 0..511) -> 33.3 KB -> 4 blocks/CU.
// MFMA 16x16x32 bf16 layouts (verified): A[m=lane&15][k=(lane>>4)*8+j];
// C/D col=lane&15, row=(lane>>4)*4+reg.
__global__ __launch_bounds__(256, 3) void expert_ffn(const float* __restrict__ x,
                                                     const uint4* __restrict__ W1f,
                                                     const uint4* __restrict__ W2f,
                                                     const float* __restrict__ b1,
                                                     const float* __restrict__ b2,
                                                     const int* __restrict__ cnt,
                                                     const int* __restrict__ offs,
                                                     const int* __restrict__ tileOffs,
                                                     const int* __restrict__ perm,
                                                     const float* __restrict__ pgate,
                                                     float* __restrict__ out) {
    __shared__ unsigned short smem[TM][DHID + 8];   // 33,280 B: xs then hs
    __shared__ int toks[TM];
    __shared__ float gs[TM];
    __shared__ int tOffs[NEXP + 1];

    int tid = threadIdx.x;
    if (tid <= NEXP) tOffs[tid] = tileOffs[tid];
    __syncthreads();
    int bid = blockIdx.x;
    if (bid >= tOffs[NEXP]) return;
    // largest e with tOffs[e] <= bid (empty experts have zero-width ranges)
    int lo = 0, hi = NEXP;
    while (hi - lo > 1) { int mid = (lo + hi) >> 1; if (tOffs[mid] <= bid) lo = mid; else hi = mid; }
    int e = lo;
    int ne = cnt[e];
    int tile0 = (bid - tOffs[e]) * TM;

    if (tid < TM) {
        int idx = tile0 + tid;
        if (idx < ne) {
            int p = offs[e] + idx;
            toks[tid] = perm[p]; gs[tid] = pgate[p];
        } else {
            toks[tid] = 0; gs[tid] = 0.0f;   // padded slot: gate 0 -> no-op add
        }
    }
    __syncthreads();
    {   // gather x rows -> LDS bf16 (cols 0..255)
        int row = tid >> 3, c0 = (tid & 7) * 32;
        const float4* src = (const float4*)(x + (size_t)toks[row] * DIN + c0);
        unsigned* dst = (unsigned*)&smem[row][c0];
#pragma unroll
        for (int i = 0; i < 8; ++i) {
            float4 v = src[i];
            dst[2 * i]     = pack2(v.x, v.y);
            dst[2 * i + 1] = pack2(v.z, v.w);
        }
    }
    __syncthreads();

    int w = tid >> 6, lane = tid & 63;
    int quad = lane >> 4, lr = lane & 15;

    // ---- pull entire X tile into regs (both m-tiles, all K) ----
    short8 a1[2][8];
#pragma unroll
    for (int mt = 0; mt < 2; ++mt)
#pragma unroll
        for (int kk = 0; kk < 8; ++kk)
            a1[mt][kk] = *(const short8*)&smem[mt * 16 + lr][kk * 32 + quad * 8];
    __syncthreads();   // xs fully consumed; smem becomes hs

    // ---- layer 1: H = relu(X @ W1[e] + b1[e]); wave w -> n in [w*128,(w+1)*128)
    for (int i = 0; i < 8; ++i) {
        int n = w * 128 + i * 16;
        const uint4* bp = W1f + (size_t)e * 16384 + (size_t)(n >> 4) * 512 + lane;
        f32x4 acc0 = {0.0f, 0.0f, 0.0f, 0.0f}, acc1 = {0.0f, 0.0f, 0.0f, 0.0f};
#pragma unroll
        for (int kk = 0; kk < 8; ++kk) {
            short8 b = __builtin_bit_cast(short8, bp[kk * 64]);
            acc0 = __builtin_amdgcn_mfma_f32_16x16x32_bf16(a1[0][kk], b, acc0, 0, 0, 0);
            acc1 = __builtin_amdgcn_mfma_f32_16x16x32_bf16(a1[1][kk], b, acc1, 0, 0, 0);
        }
        float bias = b1[e * DHID + n + lr];
#pragma unroll
        for (int r = 0; r < 4; ++r) {
            smem[quad * 4 + r][n + lr]      = f2bf(fmaxf(acc0[r] + bias, 0.0f));
            smem[16 + quad * 4 + r][n + lr] = f2bf(fmaxf(acc1[r] + bias, 0.0f));
        }
    }
    __syncthreads();

    // ---- layer 2: Y = H @ W2[e] + b2[e]; wave w -> n in [w*64, w*64+64)
    f32x4 acc[4][2];
#pragma unroll
    for (int i = 0; i < 4; ++i)
#pragma unroll
        for (int mt = 0; mt < 2; ++mt)
            acc[i][mt] = (f32x4){0.0f, 0.0f, 0.0f, 0.0f};
    for (int h = 0; h < 2; ++h) {          // K halves: regs for 8 k-chunks each
        short8 a2[2][8];
#pragma unroll
        for (int mt = 0; mt < 2; ++mt)
#pragma unroll
            for (int kk = 0; kk < 8; ++kk)
                a2[mt][kk] = *(const short8*)&smem[mt * 16 + lr][h * 256 + kk * 32 + quad * 8];
#pragma unroll
        for (int i = 0; i < 4; ++i) {
            int ng = w * 4 + i;            // global 16-wide n-tile
            const uint4* bp = W2f + (size_t)e * 16384 + (size_t)ng * 1024 + (size_t)h * 512 + lane;
#pragma unroll
            for (int kk = 0; kk < 8; ++kk) {
                short8 b = __builtin_bit_cast(short8, bp[kk * 64]);
                acc[i][0] = __builtin_amdgcn_mfma_f32_16x16x32_bf16(a2[0][kk], b, acc[i][0], 0, 0, 0);
                acc[i][1] = __builtin_amdgcn_mfma_f32_16x16x32_bf16(a2[1][kk], b, acc[i][1], 0, 0, 0);
            }
        }
    }
    // ---- epilogue: out[tok] += gate * (y + b2) ----
#pragma unroll
    for (int i = 0; i < 4; ++i) {
        int n = w * 64 + i * 16;
        float bias = b2[e * DOUT + n + lr];
#pragma unroll
        for (int mt = 0; mt < 2; ++mt)
#pragma unroll
            for (int r = 0; r < 4; ++r) {
                int m = mt * 16 + quad * 4 + r;
                float y = acc[i][mt][r] + bias;
                atomicAdd(&out[(size_t)toks[m] * DOUT + n + lr], gs[m] * y);
            }
    }
}

// ---------------------------------------------------------------------------
extern "C" void kernel_launch(void* const* d_in, const int* in_sizes, int n_in,
                              void* d_out, int out_size, void* d_ws, size_t ws_size,
                              hipStream_t stream) {
    (void)in_sizes; (void)n_in; (void)ws_size;   // needs ws_size >= ~34.6 MB
    const float* x  = (const float*)d_in[0];
    const float* Wr = (const float*)d_in[1];
    const float* br = (const float*)d_in[2];
    const float* W1 = (const float*)d_in[3];
    const float* b1 = (const float*)d_in[4];
    const float* W2 = (const float*)d_in[5];
    const float* b2 = (const float*)d_in[6];
    float* out = (float*)d_out;
    char* ws = (char*)d_ws;

    uint4* W1f     = (uint4*)(ws + OFF_W1F);
    uint4* W2f     = (uint4*)(ws + OFF_W2F);
    int*   cnt     = (int*)(ws + OFF_CNT);
    int*   cursor  = (int*)(ws + OFF_CUR);
    int*   offs    = (int*)(ws + OFF_OFFS);
    int*   tileOff = (int*)(ws + OFF_TILE);
    int*   topk_e  = (int*)(ws + OFF_TOPKE);
    float* topk_g  = (float*)(ws + OFF_TOPKG);
    int*   perm    = (int*)(ws + OFF_PERM);
    float* pgate   = (float*)(ws + OFF_PGATE);

    hipMemsetAsync(out, 0, (size_t)out_size * sizeof(float), stream);
    hipMemsetAsync(ws + OFF_CNT, 0, 512, stream);   // cnt + cursor

    prep_weights<<<8192, 256, 0, stream>>>(W1, W2, W1f, W2f);
    router_kernel<<<T_TOK / 64, 256, 0, stream>>>(x, Wr, br, topk_e, topk_g, cnt);
    scan_kernel<<<1, 64, 0, stream>>>(cnt, offs, tileOff, cursor);
    scatter_kernel<<<T_TOK / 256, 256, 0, stream>>>(topk_e, topk_g, offs, cursor, perm, pgate);
    expert_ffn<<<MAXTILES, 256, 0, stream>>>(x, W1f, W2f, b1, b2, cnt, offs, tileOff,
                                             perm, pgate, out);
}